// Round 1
// baseline (758.807 us; speedup 1.0000x reference)
//
#include <hip/hip_runtime.h>
#include <math.h>

#define NN 50000
#define EE 800000
#define DD 128
#define SLOPE 0.2f

static __device__ __forceinline__ float wred_max(float v) {
#pragma unroll
    for (int m = 1; m < 64; m <<= 1) v = fmaxf(v, __shfl_xor(v, m, 64));
    return v;
}
static __device__ __forceinline__ float wred_sum(float v) {
#pragma unroll
    for (int m = 1; m < 64; m <<= 1) v += __shfl_xor(v, m, 64);
    return v;
}

// ---------------- CSR build ----------------
__global__ void k_degree(const int* __restrict__ dstv, int* __restrict__ deg) {
    int i = blockIdx.x * blockDim.x + threadIdx.x;
    if (i < EE) atomicAdd(&deg[dstv[i]], 1);
}

__global__ void k_blocksum(const int* __restrict__ deg, int* __restrict__ bsum) {
    int t = threadIdx.x;
    int idx = blockIdx.x * 256 + t;
    int v = (idx < NN) ? deg[idx] : 0;
#pragma unroll
    for (int m = 1; m < 64; m <<= 1) v += __shfl_xor(v, m, 64);
    __shared__ int part[4];
    if ((t & 63) == 0) part[t >> 6] = v;
    __syncthreads();
    if (t == 0) bsum[blockIdx.x] = part[0] + part[1] + part[2] + part[3];
}

__global__ void k_scan_bsum(const int* __restrict__ bsum, int* __restrict__ boff, int nb) {
    __shared__ int sd[2][256];
    int t = threadIdx.x;
    int v = (t < nb) ? bsum[t] : 0;
    sd[0][t] = v;
    __syncthreads();
    int s = 0;
    for (int off = 1; off < 256; off <<= 1) {
        int x = sd[s][t];
        if (t >= off) x += sd[s][t - off];
        sd[s ^ 1][t] = x;
        s ^= 1;
        __syncthreads();
    }
    if (t < nb) boff[t] = sd[s][t] - v;  // exclusive
}

__global__ void k_scan_final(const int* __restrict__ deg, const int* __restrict__ boff,
                             int* __restrict__ offs, int* __restrict__ cursor) {
    __shared__ int sd[2][256];
    int t = threadIdx.x;
    int idx = blockIdx.x * 256 + t;
    int v = (idx < NN) ? deg[idx] : 0;
    sd[0][t] = v;
    __syncthreads();
    int s = 0;
    for (int off = 1; off < 256; off <<= 1) {
        int x = sd[s][t];
        if (t >= off) x += sd[s][t - off];
        sd[s ^ 1][t] = x;
        s ^= 1;
        __syncthreads();
    }
    int incl = sd[s][t];
    int base = boff[blockIdx.x];
    if (idx < NN) {
        offs[idx + 1] = base + incl;
        cursor[idx] = base + incl - v;
    }
    if (idx == 0) offs[0] = 0;
}

__global__ void k_scatter(const int* __restrict__ srcv, const int* __restrict__ dstv,
                          int* __restrict__ cursor, int* __restrict__ csr_src,
                          int* __restrict__ epos) {
    int i = blockIdx.x * blockDim.x + threadIdx.x;
    if (i < EE) {
        int p = atomicAdd(&cursor[dstv[i]], 1);
        csr_src[p] = srcv[i];
        epos[i] = p;
    }
}

// ---------------- fused 3-matrix GEMM: O_w = X @ W_w  (N x 128 x 128) ----------------
__global__ __launch_bounds__(256) void k_gemm3(
    const float* __restrict__ X,
    const float* __restrict__ W0, const float* __restrict__ W1, const float* __restrict__ W2,
    float* __restrict__ O0, float* __restrict__ O1, float* __restrict__ O2) {
    __shared__ float xs[64][DD + 4];
    __shared__ float ws[32][DD + 4];
    int t = threadIdx.x;
    int m0 = blockIdx.x * 64;

    // load X tile (64 x 128), zero-fill OOB rows
#pragma unroll
    for (int r = 0; r < 8; r++) {
        int flat = r * 256 + t;
        int node = flat >> 5;
        int c4 = (flat & 31) << 2;
        float4 v = make_float4(0.f, 0.f, 0.f, 0.f);
        if (m0 + node < NN)
            v = *reinterpret_cast<const float4*>(X + (size_t)(m0 + node) * DD + c4);
        xs[node][c4] = v.x; xs[node][c4 + 1] = v.y; xs[node][c4 + 2] = v.z; xs[node][c4 + 3] = v.w;
    }

    int tx = t & 15, ty = t >> 4;
    const float* Ws[3] = {W0, W1, W2};
    float* Os[3] = {O0, O1, O2};

#pragma unroll
    for (int w = 0; w < 3; w++) {
        const float* W = Ws[w];
        float acc[4][8];
#pragma unroll
        for (int i = 0; i < 4; i++)
#pragma unroll
            for (int j = 0; j < 8; j++) acc[i][j] = 0.f;

        for (int k0 = 0; k0 < DD; k0 += 32) {
            __syncthreads();
#pragma unroll
            for (int q = 0; q < 4; q++) {
                int flat = q * 256 + t;
                int row = flat >> 5;
                int c4 = (flat & 31) << 2;
                float4 v = *reinterpret_cast<const float4*>(W + (size_t)(k0 + row) * DD + c4);
                ws[row][c4] = v.x; ws[row][c4 + 1] = v.y; ws[row][c4 + 2] = v.z; ws[row][c4 + 3] = v.w;
            }
            __syncthreads();
#pragma unroll
            for (int kk = 0; kk < 32; kk++) {
                float a0 = xs[ty * 4 + 0][k0 + kk];
                float a1 = xs[ty * 4 + 1][k0 + kk];
                float a2 = xs[ty * 4 + 2][k0 + kk];
                float a3 = xs[ty * 4 + 3][k0 + kk];
                float b[8];
#pragma unroll
                for (int j = 0; j < 8; j++) b[j] = ws[kk][tx + 16 * j];
#pragma unroll
                for (int j = 0; j < 8; j++) {
                    acc[0][j] += a0 * b[j];
                    acc[1][j] += a1 * b[j];
                    acc[2][j] += a2 * b[j];
                    acc[3][j] += a3 * b[j];
                }
            }
        }
#pragma unroll
        for (int i = 0; i < 4; i++) {
            int node = m0 + ty * 4 + i;
            if (node < NN) {
#pragma unroll
                for (int j = 0; j < 8; j++)
                    Os[w][(size_t)node * DD + tx + 16 * j] = acc[i][j];
            }
        }
    }
}

// ---------------- edge logits: e = leakyrelu(xl[src]+xr[dst]) . att, scattered to CSR order ----------------
__global__ __launch_bounds__(256) void k_logits(
    const int* __restrict__ srcv, const int* __restrict__ dstv,
    const float* __restrict__ xl, const float* __restrict__ xr,
    const float* __restrict__ att, const int* __restrict__ epos,
    float* __restrict__ ecsr) {
    int g = blockIdx.x * blockDim.x + threadIdx.x;
    int eid = g >> 5;
    int lane = g & 31;
    if (eid >= EE) return;
    int s = srcv[eid], d = dstv[eid];
    float4 a = *reinterpret_cast<const float4*>(xl + (size_t)s * DD + lane * 4);
    float4 b = *reinterpret_cast<const float4*>(xr + (size_t)d * DD + lane * 4);
    float4 w = *reinterpret_cast<const float4*>(att + lane * 4);
    float sx = a.x + b.x, sy = a.y + b.y, sz = a.z + b.z, sw = a.w + b.w;
    sx = (sx > 0.f) ? sx : SLOPE * sx;
    sy = (sy > 0.f) ? sy : SLOPE * sy;
    sz = (sz > 0.f) ? sz : SLOPE * sz;
    sw = (sw > 0.f) ? sw : SLOPE * sw;
    float v = sx * w.x + sy * w.y + sz * w.z + sw * w.w;
#pragma unroll
    for (int m = 1; m < 32; m <<= 1) v += __shfl_xor(v, m, 64);
    if (lane == 0) ecsr[epos[eid]] = v;
}

// ---------------- per-node segment softmax + weighted aggregate + combine (+relu) ----------------
__global__ __launch_bounds__(256) void k_agg(
    const int* __restrict__ offs, const int* __restrict__ csr_src,
    const float* __restrict__ ecsr, const float* __restrict__ xl,
    const float* __restrict__ lin, const float* __restrict__ b,
    const float* __restrict__ blin, float* __restrict__ hout) {
    int wid = (blockIdx.x * blockDim.x + threadIdx.x) >> 6;
    int lane = threadIdx.x & 63;
    if (wid >= NN) return;
    int start = offs[wid];
    int deg = offs[wid + 1] - start;

    float m = -INFINITY;
    for (int j = lane; j < deg; j += 64) m = fmaxf(m, ecsr[start + j]);
    m = wred_max(m);
    float ssum = 0.f;
    for (int j = lane; j < deg; j += 64) ssum += __expf(ecsr[start + j] - m);
    ssum = wred_sum(ssum);
    float inv = 1.f / (ssum + 1e-16f);

    int d0 = lane * 2;
    float accx = 0.f, accy = 0.f;
    for (int base = 0; base < deg; base += 64) {
        int j = base + lane;
        float p = 0.f;
        int sv = 0;
        if (j < deg) {
            p = __expf(ecsr[start + j] - m);
            sv = csr_src[start + j];
        }
        int cnt = min(64, deg - base);
        for (int q = 0; q < cnt; q++) {
            float alpha = __shfl(p, q, 64) * inv;
            int sq = __shfl(sv, q, 64);
            float2 v = *reinterpret_cast<const float2*>(xl + (size_t)sq * DD + d0);
            accx += alpha * v.x;
            accy += alpha * v.y;
        }
    }
    float2 l = *reinterpret_cast<const float2*>(lin + (size_t)wid * DD + d0);
    float o0 = accx + b[d0] + l.x + blin[d0];
    float o1 = accy + b[d0 + 1] + l.y + blin[d0 + 1];
    o0 = fmaxf(o0, 0.f);
    o1 = fmaxf(o1, 0.f);
    *reinterpret_cast<float2*>(hout + (size_t)wid * DD + d0) = make_float2(o0, o1);
}

// ---------------- output layer: three N x 128 matvecs ----------------
__global__ __launch_bounds__(256) void k_outvec(
    const float* __restrict__ H, const float* __restrict__ Wlo,
    const float* __restrict__ Wro, const float* __restrict__ Wlino,
    const float* __restrict__ blino,
    float* __restrict__ xlo, float* __restrict__ xro, float* __restrict__ lino) {
    int wid = (blockIdx.x * blockDim.x + threadIdx.x) >> 6;
    int lane = threadIdx.x & 63;
    if (wid >= NN) return;
    float2 h = *reinterpret_cast<const float2*>(H + (size_t)wid * DD + lane * 2);
    float2 w0 = *reinterpret_cast<const float2*>(Wlo + lane * 2);
    float2 w1 = *reinterpret_cast<const float2*>(Wro + lane * 2);
    float2 w2 = *reinterpret_cast<const float2*>(Wlino + lane * 2);
    float v0 = h.x * w0.x + h.y * w0.y;
    float v1 = h.x * w1.x + h.y * w1.y;
    float v2 = h.x * w2.x + h.y * w2.y;
    v0 = wred_sum(v0);
    v1 = wred_sum(v1);
    v2 = wred_sum(v2);
    if (lane == 0) {
        xlo[wid] = v0;
        xro[wid] = v1;
        lino[wid] = v2 + blino[0];
    }
}

__global__ __launch_bounds__(256) void k_logits_out(
    const int* __restrict__ srcv, const int* __restrict__ dstv,
    const float* __restrict__ xlo, const float* __restrict__ xro,
    const float* __restrict__ atto, const int* __restrict__ epos,
    float* __restrict__ ecsr) {
    int i = blockIdx.x * blockDim.x + threadIdx.x;
    if (i < EE) {
        float sm = xlo[srcv[i]] + xro[dstv[i]];
        float v = ((sm > 0.f) ? sm : SLOPE * sm) * atto[0];
        ecsr[epos[i]] = v;
    }
}

__global__ __launch_bounds__(256) void k_agg_out(
    const int* __restrict__ offs, const int* __restrict__ csr_src,
    const float* __restrict__ ecsr, const float* __restrict__ xlo,
    const float* __restrict__ lino, const float* __restrict__ bo,
    float* __restrict__ out) {
    int wid = (blockIdx.x * blockDim.x + threadIdx.x) >> 6;
    int lane = threadIdx.x & 63;
    if (wid >= NN) return;
    int start = offs[wid];
    int deg = offs[wid + 1] - start;
    float m = -INFINITY;
    for (int j = lane; j < deg; j += 64) m = fmaxf(m, ecsr[start + j]);
    m = wred_max(m);
    float ssum = 0.f, num = 0.f;
    for (int j = lane; j < deg; j += 64) {
        float p = __expf(ecsr[start + j] - m);
        ssum += p;
        num += p * xlo[csr_src[start + j]];
    }
    ssum = wred_sum(ssum);
    num = wred_sum(num);
    if (lane == 0) out[wid] = num / (ssum + 1e-16f) + bo[0] + lino[wid];
}

extern "C" void kernel_launch(void* const* d_in, const int* in_sizes, int n_in,
                              void* d_out, int out_size, void* d_ws, size_t ws_size,
                              hipStream_t stream) {
    const float* x = (const float*)d_in[0];
    const int* ei = (const int*)d_in[1];
    const int* srcv = ei;
    const int* dstv = ei + EE;
    const float* Wl1 = (const float*)d_in[2];
    const float* Wr1 = (const float*)d_in[3];
    const float* att1 = (const float*)d_in[4];
    const float* b1 = (const float*)d_in[5];
    const float* Wlin1 = (const float*)d_in[6];
    const float* blin1 = (const float*)d_in[7];
    const float* Wl2 = (const float*)d_in[8];
    const float* Wr2 = (const float*)d_in[9];
    const float* att2 = (const float*)d_in[10];
    const float* b2 = (const float*)d_in[11];
    const float* Wlin2 = (const float*)d_in[12];
    const float* blin2 = (const float*)d_in[13];
    const float* Wlo = (const float*)d_in[14];
    const float* Wro = (const float*)d_in[15];
    const float* atto = (const float*)d_in[16];
    const float* bo = (const float*)d_in[17];
    const float* Wlino = (const float*)d_in[18];
    const float* blino = (const float*)d_in[19];

    char* w = (char*)d_ws;
    auto alloc = [&](size_t bytes) {
        void* p = (void*)w;
        w += (bytes + 255) & ~(size_t)255;
        return p;
    };
    float* xl = (float*)alloc((size_t)NN * DD * 4);
    float* xr = (float*)alloc((size_t)NN * DD * 4);
    float* lin = (float*)alloc((size_t)NN * DD * 4);
    float* h = (float*)alloc((size_t)NN * DD * 4);
    float* ecsr = (float*)alloc((size_t)EE * 4);
    float* xlo = (float*)alloc((size_t)NN * 4);
    float* xro = (float*)alloc((size_t)NN * 4);
    float* lino = (float*)alloc((size_t)NN * 4);
    int* deg = (int*)alloc((size_t)NN * 4);
    int* offs = (int*)alloc((size_t)(NN + 1) * 4);
    int* cursor = (int*)alloc((size_t)NN * 4);
    int* bsum = (int*)alloc(256 * 4);
    int* boff = (int*)alloc(256 * 4);
    int* csr_src = (int*)alloc((size_t)EE * 4);
    int* epos = (int*)alloc((size_t)EE * 4);

    const int NB = (NN + 255) / 256;  // 196

    // CSR build (graph fixed across layers)
    hipMemsetAsync(deg, 0, (size_t)NN * 4, stream);
    k_degree<<<(EE + 255) / 256, 256, 0, stream>>>(dstv, deg);
    k_blocksum<<<NB, 256, 0, stream>>>(deg, bsum);
    k_scan_bsum<<<1, 256, 0, stream>>>(bsum, boff, NB);
    k_scan_final<<<NB, 256, 0, stream>>>(deg, boff, offs, cursor);
    k_scatter<<<(EE + 255) / 256, 256, 0, stream>>>(srcv, dstv, cursor, csr_src, epos);

    const int GEMM_GRID = (NN + 63) / 64;
    const int LOGIT_GRID = (EE * 32 + 255) / 256;
    const int NODE_GRID = (NN * 64 + 255) / 256;

    // layer 1
    k_gemm3<<<GEMM_GRID, 256, 0, stream>>>(x, Wl1, Wr1, Wlin1, xl, xr, lin);
    k_logits<<<LOGIT_GRID, 256, 0, stream>>>(srcv, dstv, xl, xr, att1, epos, ecsr);
    k_agg<<<NODE_GRID, 256, 0, stream>>>(offs, csr_src, ecsr, xl, lin, b1, blin1, h);
    // layer 2
    k_gemm3<<<GEMM_GRID, 256, 0, stream>>>(h, Wl2, Wr2, Wlin2, xl, xr, lin);
    k_logits<<<LOGIT_GRID, 256, 0, stream>>>(srcv, dstv, xl, xr, att2, epos, ecsr);
    k_agg<<<NODE_GRID, 256, 0, stream>>>(offs, csr_src, ecsr, xl, lin, b2, blin2, h);
    // output layer
    k_outvec<<<NODE_GRID, 256, 0, stream>>>(h, Wlo, Wro, Wlino, blino, xlo, xro, lino);
    k_logits_out<<<(EE + 255) / 256, 256, 0, stream>>>(srcv, dstv, xlo, xro, atto, epos, ecsr);
    k_agg_out<<<NODE_GRID, 256, 0, stream>>>(offs, csr_src, ecsr, xlo, lino, bo, (float*)d_out);
}

// Round 2
// 295.053 us; speedup vs baseline: 2.5718x; 2.5718x over previous
//
#include <hip/hip_runtime.h>
#include <hip/hip_bf16.h>
#include <math.h>

#define NN 50000
#define EE 800000
#define DD 128
#define SLOPE 0.2f

typedef __attribute__((ext_vector_type(8))) short short8;   // 8 bf16 (4 VGPRs)
typedef __attribute__((ext_vector_type(4))) float f32x4;    // MFMA acc

static __device__ __forceinline__ float wred_max(float v) {
#pragma unroll
    for (int m = 1; m < 64; m <<= 1) v = fmaxf(v, __shfl_xor(v, m, 64));
    return v;
}
static __device__ __forceinline__ float wred_sum(float v) {
#pragma unroll
    for (int m = 1; m < 64; m <<= 1) v += __shfl_xor(v, m, 64);
    return v;
}

static __device__ __forceinline__ ushort f2bf(float f) {
    __hip_bfloat16 b = __float2bfloat16(f);
    return *reinterpret_cast<ushort*>(&b);
}
static __device__ __forceinline__ float bf2f(ushort u) {
    return __uint_as_float(((unsigned int)u) << 16);
}

// ---------------- CSR build ----------------
__global__ void k_degree(const int* __restrict__ dstv, int* __restrict__ deg) {
    int i = blockIdx.x * blockDim.x + threadIdx.x;
    if (i < EE) atomicAdd(&deg[dstv[i]], 1);
}

__global__ void k_blocksum(const int* __restrict__ deg, int* __restrict__ bsum) {
    int t = threadIdx.x;
    int idx = blockIdx.x * 256 + t;
    int v = (idx < NN) ? deg[idx] : 0;
#pragma unroll
    for (int m = 1; m < 64; m <<= 1) v += __shfl_xor(v, m, 64);
    __shared__ int part[4];
    if ((t & 63) == 0) part[t >> 6] = v;
    __syncthreads();
    if (t == 0) bsum[blockIdx.x] = part[0] + part[1] + part[2] + part[3];
}

__global__ void k_scan_bsum(const int* __restrict__ bsum, int* __restrict__ boff, int nb) {
    __shared__ int sd[2][256];
    int t = threadIdx.x;
    int v = (t < nb) ? bsum[t] : 0;
    sd[0][t] = v;
    __syncthreads();
    int s = 0;
    for (int off = 1; off < 256; off <<= 1) {
        int x = sd[s][t];
        if (t >= off) x += sd[s][t - off];
        sd[s ^ 1][t] = x;
        s ^= 1;
        __syncthreads();
    }
    if (t < nb) boff[t] = sd[s][t] - v;  // exclusive
}

__global__ void k_scan_final(const int* __restrict__ deg, const int* __restrict__ boff,
                             int* __restrict__ offs, int* __restrict__ cursor) {
    __shared__ int sd[2][256];
    int t = threadIdx.x;
    int idx = blockIdx.x * 256 + t;
    int v = (idx < NN) ? deg[idx] : 0;
    sd[0][t] = v;
    __syncthreads();
    int s = 0;
    for (int off = 1; off < 256; off <<= 1) {
        int x = sd[s][t];
        if (t >= off) x += sd[s][t - off];
        sd[s ^ 1][t] = x;
        s ^= 1;
        __syncthreads();
    }
    int incl = sd[s][t];
    int base = boff[blockIdx.x];
    if (idx < NN) {
        offs[idx + 1] = base + incl;
        cursor[idx] = base + incl - v;
    }
    if (idx == 0) offs[0] = 0;
}

__global__ void k_scatter(const int* __restrict__ srcv, const int* __restrict__ dstv,
                          int* __restrict__ cursor, int* __restrict__ csr_src) {
    int i = blockIdx.x * blockDim.x + threadIdx.x;
    if (i < EE) {
        int p = atomicAdd(&cursor[dstv[i]], 1);
        csr_src[p] = srcv[i];
    }
}

// ---------------- weight convert: Wt[i][n][k] = bf16(W_i[k][n]) ----------------
__global__ __launch_bounds__(256) void k_wconvert(
    const float* __restrict__ W0, const float* __restrict__ W1, const float* __restrict__ W2,
    const float* __restrict__ W3, const float* __restrict__ W4, const float* __restrict__ W5,
    ushort* __restrict__ Wt) {
    int idx = blockIdx.x * 256 + threadIdx.x;  // 6*16384
    int i = idx >> 14;
    int r = idx & 16383;
    int n = r >> 7;
    int k = r & 127;
    const float* Ws[6] = {W0, W1, W2, W3, W4, W5};
    Wt[idx] = f2bf(Ws[i][k * DD + n]);
}

// ---------------- MFMA 3-matrix GEMM: O_w = X @ W_w (bf16 in, fp32 acc) ----------------
// block=256 (4 waves), each wave: 32 rows x 128 cols. K=128.
__global__ __launch_bounds__(256) void k_gemm3m(
    const float* __restrict__ X,      // [NN][128] fp32
    const ushort* __restrict__ Wt,    // [3][128][128] bf16, [n][k] layout
    ushort* __restrict__ O0b,         // xl bf16
    float* __restrict__ O1,           // xr fp32
    float* __restrict__ O2) {         // lin fp32
    int t = threadIdx.x;
    int wid = t >> 6, lane = t & 63;
    int m0 = blockIdx.x * 128 + wid * 32;
    int qrow = lane & 15, kg = lane >> 4;

    // A fragments: 2 m-tiles x 4 k-steps, converted fp32->bf16 inline
    short8 afrag[2][4];
#pragma unroll
    for (int mg = 0; mg < 2; mg++) {
#pragma unroll
        for (int ks = 0; ks < 4; ks++) {
            int row = m0 + mg * 16 + qrow;
            row = (row < NN) ? row : (NN - 1);  // clamp (stores predicated)
            const float* p = X + (size_t)row * DD + ks * 32 + kg * 8;
            float4 u0 = *reinterpret_cast<const float4*>(p);
            float4 u1 = *reinterpret_cast<const float4*>(p + 4);
            short8 s;
            s[0] = (short)f2bf(u0.x); s[1] = (short)f2bf(u0.y);
            s[2] = (short)f2bf(u0.z); s[3] = (short)f2bf(u0.w);
            s[4] = (short)f2bf(u1.x); s[5] = (short)f2bf(u1.y);
            s[6] = (short)f2bf(u1.z); s[7] = (short)f2bf(u1.w);
            afrag[mg][ks] = s;
        }
    }

#pragma unroll
    for (int w = 0; w < 3; w++) {
        const ushort* Wb = Wt + (size_t)w * DD * DD;
        f32x4 acc[2][8];
#pragma unroll
        for (int mg = 0; mg < 2; mg++)
#pragma unroll
            for (int ng = 0; ng < 8; ng++) acc[mg][ng] = (f32x4)(0.f);

#pragma unroll
        for (int ks = 0; ks < 4; ks++) {
            short8 bfrag[8];
#pragma unroll
            for (int ng = 0; ng < 8; ng++)
                bfrag[ng] = *reinterpret_cast<const short8*>(
                    Wb + (size_t)(ng * 16 + qrow) * DD + ks * 32 + kg * 8);
#pragma unroll
            for (int mg = 0; mg < 2; mg++)
#pragma unroll
                for (int ng = 0; ng < 8; ng++)
                    acc[mg][ng] = __builtin_amdgcn_mfma_f32_16x16x32_bf16(
                        afrag[mg][ks], bfrag[ng], acc[mg][ng], 0, 0, 0);
        }

        // store: row = m0 + mg*16 + kg*4 + r, col = ng*16 + qrow
#pragma unroll
        for (int mg = 0; mg < 2; mg++) {
#pragma unroll
            for (int r = 0; r < 4; r++) {
                int row = m0 + mg * 16 + kg * 4 + r;
                if (row < NN) {
#pragma unroll
                    for (int ng = 0; ng < 8; ng++) {
                        int col = ng * 16 + qrow;
                        float v = acc[mg][ng][r];
                        if (w == 0) O0b[(size_t)row * DD + col] = f2bf(v);
                        else if (w == 1) O1[(size_t)row * DD + col] = v;
                        else O2[(size_t)row * DD + col] = v;
                    }
                }
            }
        }
    }
}

// ---------------- fused logits + online softmax + aggregate + combine (+relu) ----------------
// wave per dst node; quarter-wave (16 lanes x 8 cols) processes one edge; 4 edges in flight.
__global__ __launch_bounds__(256) void k_fused(
    const int* __restrict__ offs, const int* __restrict__ csr_src,
    const ushort* __restrict__ xlb,  // [NN][128] bf16 (messages + logit left)
    const float* __restrict__ xr,    // [NN][128] fp32 (logit right)
    const float* __restrict__ att,
    const float* __restrict__ lin, const float* __restrict__ bb,
    const float* __restrict__ blin, float* __restrict__ hout) {
    int wid = (blockIdx.x * blockDim.x + threadIdx.x) >> 6;
    int lane = threadIdx.x & 63;
    if (wid >= NN) return;
    int q = lane >> 4;    // quarter 0..3
    int ql = lane & 15;
    int c0 = ql * 8;

    float xrv[8], av[8];
    {
        float4 t0 = *reinterpret_cast<const float4*>(xr + (size_t)wid * DD + c0);
        float4 t1 = *reinterpret_cast<const float4*>(xr + (size_t)wid * DD + c0 + 4);
        xrv[0] = t0.x; xrv[1] = t0.y; xrv[2] = t0.z; xrv[3] = t0.w;
        xrv[4] = t1.x; xrv[5] = t1.y; xrv[6] = t1.z; xrv[7] = t1.w;
        float4 a0 = *reinterpret_cast<const float4*>(att + c0);
        float4 a1 = *reinterpret_cast<const float4*>(att + c0 + 4);
        av[0] = a0.x; av[1] = a0.y; av[2] = a0.z; av[3] = a0.w;
        av[4] = a1.x; av[5] = a1.y; av[6] = a1.z; av[7] = a1.w;
    }

    int start = offs[wid];
    int deg = offs[wid + 1] - start;

    float m = -INFINITY, ss = 0.f;
    float acc[8];
#pragma unroll
    for (int c = 0; c < 8; c++) acc[c] = 0.f;

    for (int j = q; j < deg; j += 4) {
        int s = csr_src[start + j];
        uint4 xp = *reinterpret_cast<const uint4*>(xlb + (size_t)s * DD + c0);
        float xv[8];
        xv[0] = bf2f((ushort)(xp.x & 0xffff)); xv[1] = bf2f((ushort)(xp.x >> 16));
        xv[2] = bf2f((ushort)(xp.y & 0xffff)); xv[3] = bf2f((ushort)(xp.y >> 16));
        xv[4] = bf2f((ushort)(xp.z & 0xffff)); xv[5] = bf2f((ushort)(xp.z >> 16));
        xv[6] = bf2f((ushort)(xp.w & 0xffff)); xv[7] = bf2f((ushort)(xp.w >> 16));
        float v = 0.f;
#pragma unroll
        for (int c = 0; c < 8; c++) {
            float u = xv[c] + xrv[c];
            u = (u > 0.f) ? u : SLOPE * u;
            v += u * av[c];
        }
        // reduce within 16-lane quarter
#pragma unroll
        for (int msk = 1; msk < 16; msk <<= 1) v += __shfl_xor(v, msk, 64);
        float nm = fmaxf(m, v);
        float sc = __expf(m - nm);  // m=-inf, nm finite -> 0
        float p = __expf(v - nm);
        ss = ss * sc + p;
#pragma unroll
        for (int c = 0; c < 8; c++) acc[c] = acc[c] * sc + p * xv[c];
        m = nm;
    }

    // merge the 4 quarter-states (masks 16, 32)
#pragma unroll
    for (int msk = 16; msk < 64; msk <<= 1) {
        float om = __shfl_xor(m, msk, 64);
        float os = __shfl_xor(ss, msk, 64);
        float oacc[8];
#pragma unroll
        for (int c = 0; c < 8; c++) oacc[c] = __shfl_xor(acc[c], msk, 64);
        float nm = fmaxf(m, om);
        float scS = (m == nm) ? 1.f : __expf(m - nm);    // handles -inf==-inf -> 1 (ss=0)
        float scO = (om == nm) ? 1.f : __expf(om - nm);
        ss = ss * scS + os * scO;
#pragma unroll
        for (int c = 0; c < 8; c++) acc[c] = acc[c] * scS + oacc[c] * scO;
        m = nm;
    }

    if (q == 0) {
        float inv = 1.f / (ss + 1e-16f);
        float4 l0 = *reinterpret_cast<const float4*>(lin + (size_t)wid * DD + c0);
        float4 l1 = *reinterpret_cast<const float4*>(lin + (size_t)wid * DD + c0 + 4);
        float4 b0 = *reinterpret_cast<const float4*>(bb + c0);
        float4 b1 = *reinterpret_cast<const float4*>(bb + c0 + 4);
        float4 bl0 = *reinterpret_cast<const float4*>(blin + c0);
        float4 bl1 = *reinterpret_cast<const float4*>(blin + c0 + 4);
        float lv[8] = {l0.x, l0.y, l0.z, l0.w, l1.x, l1.y, l1.z, l1.w};
        float bv[8] = {b0.x, b0.y, b0.z, b0.w, b1.x, b1.y, b1.z, b1.w};
        float blv[8] = {bl0.x, bl0.y, bl0.z, bl0.w, bl1.x, bl1.y, bl1.z, bl1.w};
        float o[8];
#pragma unroll
        for (int c = 0; c < 8; c++) o[c] = fmaxf(acc[c] * inv + bv[c] + lv[c] + blv[c], 0.f);
        float4 s0 = make_float4(o[0], o[1], o[2], o[3]);
        float4 s1 = make_float4(o[4], o[5], o[6], o[7]);
        *reinterpret_cast<float4*>(hout + (size_t)wid * DD + c0) = s0;
        *reinterpret_cast<float4*>(hout + (size_t)wid * DD + c0 + 4) = s1;
    }
}

// ---------------- output layer: three N x 128 matvecs ----------------
__global__ __launch_bounds__(256) void k_outvec(
    const float* __restrict__ H, const float* __restrict__ Wlo,
    const float* __restrict__ Wro, const float* __restrict__ Wlino,
    const float* __restrict__ blino,
    float* __restrict__ xlo, float* __restrict__ xro, float* __restrict__ lino) {
    int wid = (blockIdx.x * blockDim.x + threadIdx.x) >> 6;
    int lane = threadIdx.x & 63;
    if (wid >= NN) return;
    float2 h = *reinterpret_cast<const float2*>(H + (size_t)wid * DD + lane * 2);
    float2 w0 = *reinterpret_cast<const float2*>(Wlo + lane * 2);
    float2 w1 = *reinterpret_cast<const float2*>(Wro + lane * 2);
    float2 w2 = *reinterpret_cast<const float2*>(Wlino + lane * 2);
    float v0 = h.x * w0.x + h.y * w0.y;
    float v1 = h.x * w1.x + h.y * w1.y;
    float v2 = h.x * w2.x + h.y * w2.y;
    v0 = wred_sum(v0);
    v1 = wred_sum(v1);
    v2 = wred_sum(v2);
    if (lane == 0) {
        xlo[wid] = v0;
        xro[wid] = v1;
        lino[wid] = v2 + blino[0];
    }
}

// ---------------- fused output-layer logits + softmax + aggregate ----------------
__global__ __launch_bounds__(256) void k_aggout(
    const int* __restrict__ offs, const int* __restrict__ csr_src,
    const float* __restrict__ xlo, const float* __restrict__ xro,
    const float* __restrict__ atto, const float* __restrict__ lino,
    const float* __restrict__ bo, float* __restrict__ out) {
    int wid = (blockIdx.x * blockDim.x + threadIdx.x) >> 6;
    int lane = threadIdx.x & 63;
    if (wid >= NN) return;
    int start = offs[wid];
    int deg = offs[wid + 1] - start;
    float xro_w = xro[wid];
    float a0 = atto[0];

    float ml = -INFINITY, sl = 0.f, nl = 0.f;
    for (int j = lane; j < deg; j += 64) {
        int s = csr_src[start + j];
        float xs = xlo[s];
        float e = xs + xro_w;
        e = (e > 0.f) ? e : SLOPE * e;
        e *= a0;
        float nm = fmaxf(ml, e);
        float sc = __expf(ml - nm);  // first iter: exp(-inf)=0
        float p = __expf(e - nm);
        sl = sl * sc + p;
        nl = nl * sc + p * xs;
        ml = nm;
    }
    // cross-lane merge
#pragma unroll
    for (int msk = 1; msk < 64; msk <<= 1) {
        float om = __shfl_xor(ml, msk, 64);
        float os = __shfl_xor(sl, msk, 64);
        float on = __shfl_xor(nl, msk, 64);
        float nm = fmaxf(ml, om);
        float scS = (ml == nm) ? 1.f : __expf(ml - nm);
        float scO = (om == nm) ? 1.f : __expf(om - nm);
        sl = sl * scS + os * scO;
        nl = nl * scS + on * scO;
        ml = nm;
    }
    if (lane == 0) out[wid] = nl / (sl + 1e-16f) + bo[0] + lino[wid];
}

extern "C" void kernel_launch(void* const* d_in, const int* in_sizes, int n_in,
                              void* d_out, int out_size, void* d_ws, size_t ws_size,
                              hipStream_t stream) {
    const float* x = (const float*)d_in[0];
    const int* ei = (const int*)d_in[1];
    const int* srcv = ei;
    const int* dstv = ei + EE;
    const float* Wl1 = (const float*)d_in[2];
    const float* Wr1 = (const float*)d_in[3];
    const float* att1 = (const float*)d_in[4];
    const float* b1 = (const float*)d_in[5];
    const float* Wlin1 = (const float*)d_in[6];
    const float* blin1 = (const float*)d_in[7];
    const float* Wl2 = (const float*)d_in[8];
    const float* Wr2 = (const float*)d_in[9];
    const float* att2 = (const float*)d_in[10];
    const float* b2 = (const float*)d_in[11];
    const float* Wlin2 = (const float*)d_in[12];
    const float* blin2 = (const float*)d_in[13];
    const float* Wlo = (const float*)d_in[14];
    const float* Wro = (const float*)d_in[15];
    const float* atto = (const float*)d_in[16];
    const float* bo = (const float*)d_in[17];
    const float* Wlino = (const float*)d_in[18];
    const float* blino = (const float*)d_in[19];

    char* w = (char*)d_ws;
    auto alloc = [&](size_t bytes) {
        void* p = (void*)w;
        w += (bytes + 255) & ~(size_t)255;
        return p;
    };
    ushort* xlb = (ushort*)alloc((size_t)NN * DD * 2);   // bf16 messages
    float* xr = (float*)alloc((size_t)NN * DD * 4);
    float* lin = (float*)alloc((size_t)NN * DD * 4);
    float* h = (float*)alloc((size_t)NN * DD * 4);
    ushort* Wt = (ushort*)alloc((size_t)6 * DD * DD * 2);
    float* xlo = (float*)alloc((size_t)NN * 4);
    float* xro = (float*)alloc((size_t)NN * 4);
    float* lino = (float*)alloc((size_t)NN * 4);
    int* deg = (int*)alloc((size_t)NN * 4);
    int* offs = (int*)alloc((size_t)(NN + 1) * 4);
    int* cursor = (int*)alloc((size_t)NN * 4);
    int* bsum = (int*)alloc(256 * 4);
    int* boff = (int*)alloc(256 * 4);
    int* csr_src = (int*)alloc((size_t)EE * 4);

    const int NB = (NN + 255) / 256;  // 196

    // CSR build
    hipMemsetAsync(deg, 0, (size_t)NN * 4, stream);
    k_degree<<<(EE + 255) / 256, 256, 0, stream>>>(dstv, deg);
    k_blocksum<<<NB, 256, 0, stream>>>(deg, bsum);
    k_scan_bsum<<<1, 256, 0, stream>>>(bsum, boff, NB);
    k_scan_final<<<NB, 256, 0, stream>>>(deg, boff, offs, cursor);
    k_scatter<<<(EE + 255) / 256, 256, 0, stream>>>(srcv, dstv, cursor, csr_src);

    // weights -> transposed bf16
    k_wconvert<<<(6 * DD * DD) / 256, 256, 0, stream>>>(Wl1, Wr1, Wlin1, Wl2, Wr2, Wlin2, Wt);

    const int GEMM_GRID = (NN + 127) / 128;          // 391
    const int NODE_GRID = (NN * 64 + 255) / 256;     // 12500

    // layer 1
    k_gemm3m<<<GEMM_GRID, 256, 0, stream>>>(x, Wt + 0 * 3 * DD * DD, xlb, xr, lin);
    k_fused<<<NODE_GRID, 256, 0, stream>>>(offs, csr_src, xlb, xr, att1, lin, b1, blin1, h);
    // layer 2
    k_gemm3m<<<GEMM_GRID, 256, 0, stream>>>(h, Wt + 1 * 3 * DD * DD, xlb, xr, lin);
    k_fused<<<NODE_GRID, 256, 0, stream>>>(offs, csr_src, xlb, xr, att2, lin, b2, blin2, h);
    // output layer
    k_outvec<<<NODE_GRID, 256, 0, stream>>>(h, Wlo, Wro, Wlino, blino, xlo, xro, lino);
    k_aggout<<<NODE_GRID, 256, 0, stream>>>(offs, csr_src, xlo, xro, atto, lino, bo, (float*)d_out);
}

// Round 3
// 235.390 us; speedup vs baseline: 3.2236x; 1.2535x over previous
//
#include <hip/hip_runtime.h>
#include <hip/hip_bf16.h>
#include <math.h>

#define NN 50000
#define EE 800000
#define DD 128
#define SLOPE 0.2f

typedef __attribute__((ext_vector_type(8))) short short8;   // 8 bf16 (4 VGPRs)
typedef __attribute__((ext_vector_type(4))) float f32x4;    // MFMA acc

static __device__ __forceinline__ float wred_sum(float v) {
#pragma unroll
    for (int m = 1; m < 64; m <<= 1) v += __shfl_xor(v, m, 64);
    return v;
}

static __device__ __forceinline__ ushort f2bf(float f) {
    __hip_bfloat16 b = __float2bfloat16(f);
    return *reinterpret_cast<ushort*>(&b);
}
static __device__ __forceinline__ float bf2f(unsigned int u) {
    return __uint_as_float((u & 0xffffu) << 16);
}
static __device__ __forceinline__ void unpack8(const uint4& xp, float* xv) {
    xv[0] = bf2f(xp.x); xv[1] = bf2f(xp.x >> 16);
    xv[2] = bf2f(xp.y); xv[3] = bf2f(xp.y >> 16);
    xv[4] = bf2f(xp.z); xv[5] = bf2f(xp.z >> 16);
    xv[6] = bf2f(xp.w); xv[7] = bf2f(xp.w >> 16);
}

// ---------------- CSR build ----------------
__global__ void k_degree(const int* __restrict__ dstv, int* __restrict__ deg,
                         int* __restrict__ epos) {
    int i = blockIdx.x * blockDim.x + threadIdx.x;
    if (i < EE) epos[i] = atomicAdd(&deg[dstv[i]], 1);
}

__global__ void k_blocksum(const int* __restrict__ deg, int* __restrict__ bsum) {
    int t = threadIdx.x;
    int idx = blockIdx.x * 256 + t;
    int v = (idx < NN) ? deg[idx] : 0;
#pragma unroll
    for (int m = 1; m < 64; m <<= 1) v += __shfl_xor(v, m, 64);
    __shared__ int part[4];
    if ((t & 63) == 0) part[t >> 6] = v;
    __syncthreads();
    if (t == 0) bsum[blockIdx.x] = part[0] + part[1] + part[2] + part[3];
}

__global__ void k_scan_bsum(const int* __restrict__ bsum, int* __restrict__ boff, int nb) {
    __shared__ int sd[2][256];
    int t = threadIdx.x;
    int v = (t < nb) ? bsum[t] : 0;
    sd[0][t] = v;
    __syncthreads();
    int s = 0;
    for (int off = 1; off < 256; off <<= 1) {
        int x = sd[s][t];
        if (t >= off) x += sd[s][t - off];
        sd[s ^ 1][t] = x;
        s ^= 1;
        __syncthreads();
    }
    if (t < nb) boff[t] = sd[s][t] - v;  // exclusive
}

__global__ void k_scan_final(const int* __restrict__ deg, const int* __restrict__ boff,
                             int* __restrict__ offs) {
    __shared__ int sd[2][256];
    int t = threadIdx.x;
    int idx = blockIdx.x * 256 + t;
    int v = (idx < NN) ? deg[idx] : 0;
    sd[0][t] = v;
    __syncthreads();
    int s = 0;
    for (int off = 1; off < 256; off <<= 1) {
        int x = sd[s][t];
        if (t >= off) x += sd[s][t - off];
        sd[s ^ 1][t] = x;
        s ^= 1;
        __syncthreads();
    }
    int incl = sd[s][t];
    int base = boff[blockIdx.x];
    if (idx < NN) offs[idx + 1] = base + incl;
    if (idx == 0) offs[0] = 0;
}

__global__ void k_scatter(const int* __restrict__ srcv, const int* __restrict__ dstv,
                          const int* __restrict__ offs, const int* __restrict__ epos,
                          int* __restrict__ csr_src) {
    int i = blockIdx.x * blockDim.x + threadIdx.x;
    if (i < EE) csr_src[offs[dstv[i]] + epos[i]] = srcv[i];
}

// ---------------- weight convert: Wt[i][n][k] = bf16(W_i[k][n]) ----------------
__global__ __launch_bounds__(256) void k_wconvert(
    const float* __restrict__ W0, const float* __restrict__ W1, const float* __restrict__ W2,
    const float* __restrict__ W3, const float* __restrict__ W4, const float* __restrict__ W5,
    ushort* __restrict__ Wt) {
    int idx = blockIdx.x * 256 + threadIdx.x;  // 6*16384
    int i = idx >> 14;
    int r = idx & 16383;
    int n = r >> 7;
    int k = r & 127;
    const float* Ws[6] = {W0, W1, W2, W3, W4, W5};
    Wt[idx] = f2bf(Ws[i][k * DD + n]);
}

// ---------------- MFMA 3-matrix GEMM with LDS-staged weights ----------------
// block=256 (4 waves), each wave: 32 rows x 128 cols. K=128.
__global__ __launch_bounds__(256) void k_gemm3m(
    const float* __restrict__ X,      // [NN][128] fp32
    const ushort* __restrict__ Wt,    // [3][128][128] bf16, [n][k] layout
    ushort* __restrict__ O0b,         // xl bf16
    float* __restrict__ O1,           // xr fp32
    float* __restrict__ O2) {         // lin fp32
    __shared__ ushort wsh[128 * 136];  // +8 shorts/row pad -> balanced banks
    int t = threadIdx.x;
    int wid = t >> 6, lane = t & 63;
    int m0 = blockIdx.x * 128 + wid * 32;
    int qrow = lane & 15, kg = lane >> 4;

    // A fragments: 2 m-tiles x 4 k-steps, converted fp32->bf16 inline
    short8 afrag[2][4];
#pragma unroll
    for (int mg = 0; mg < 2; mg++) {
#pragma unroll
        for (int ks = 0; ks < 4; ks++) {
            int row = m0 + mg * 16 + qrow;
            row = (row < NN) ? row : (NN - 1);  // clamp (stores predicated)
            const float* p = X + (size_t)row * DD + ks * 32 + kg * 8;
            float4 u0 = *reinterpret_cast<const float4*>(p);
            float4 u1 = *reinterpret_cast<const float4*>(p + 4);
            short8 s;
            s[0] = (short)f2bf(u0.x); s[1] = (short)f2bf(u0.y);
            s[2] = (short)f2bf(u0.z); s[3] = (short)f2bf(u0.w);
            s[4] = (short)f2bf(u1.x); s[5] = (short)f2bf(u1.y);
            s[6] = (short)f2bf(u1.z); s[7] = (short)f2bf(u1.w);
            afrag[mg][ks] = s;
        }
    }

    for (int w = 0; w < 3; w++) {
        __syncthreads();  // previous iter done reading wsh
        const ushort* Wb = Wt + (size_t)w * DD * DD;
#pragma unroll
        for (int i = 0; i < 8; i++) {
            int flat = i * 256 + t;       // 0..2047 chunks of 8 shorts
            int row = flat >> 4, ch = flat & 15;
            short8 v = *reinterpret_cast<const short8*>(Wb + row * DD + ch * 8);
            *reinterpret_cast<short8*>(&wsh[row * 136 + ch * 8]) = v;
        }
        __syncthreads();

        f32x4 acc[2][8];
#pragma unroll
        for (int mg = 0; mg < 2; mg++)
#pragma unroll
            for (int ng = 0; ng < 8; ng++) acc[mg][ng] = (f32x4)(0.f);

#pragma unroll
        for (int ks = 0; ks < 4; ks++) {
            short8 bfrag[8];
#pragma unroll
            for (int ng = 0; ng < 8; ng++)
                bfrag[ng] = *reinterpret_cast<const short8*>(
                    &wsh[(ng * 16 + qrow) * 136 + ks * 32 + kg * 8]);
#pragma unroll
            for (int mg = 0; mg < 2; mg++)
#pragma unroll
                for (int ng = 0; ng < 8; ng++)
                    acc[mg][ng] = __builtin_amdgcn_mfma_f32_16x16x32_bf16(
                        afrag[mg][ks], bfrag[ng], acc[mg][ng], 0, 0, 0);
        }

        // store: row = m0 + mg*16 + kg*4 + r, col = ng*16 + qrow
#pragma unroll
        for (int mg = 0; mg < 2; mg++) {
#pragma unroll
            for (int r = 0; r < 4; r++) {
                int row = m0 + mg * 16 + kg * 4 + r;
                if (row < NN) {
#pragma unroll
                    for (int ng = 0; ng < 8; ng++) {
                        int col = ng * 16 + qrow;
                        float v = acc[mg][ng][r];
                        if (w == 0) O0b[(size_t)row * DD + col] = f2bf(v);
                        else if (w == 1) O1[(size_t)row * DD + col] = v;
                        else O2[(size_t)row * DD + col] = v;
                    }
                }
            }
        }
    }
}

// ---------------- fused logits + softmax (no-max) + aggregate + combine (+relu) ----------------
// wave per dst node; quarter-wave (16 lanes x 8 cols) x 2 edges in flight.
// OUTVEC=1: layer-2 variant, fuses the three output-layer matvecs; h never stored.
template <int OUTVEC>
__global__ __launch_bounds__(256) void k_fused(
    const int* __restrict__ offs, const int* __restrict__ csr_src,
    const ushort* __restrict__ xlb,  // [NN][128] bf16 (messages + logit left)
    const float* __restrict__ xr,    // [NN][128] fp32 (logit right)
    const float* __restrict__ att,
    const float* __restrict__ lin, const float* __restrict__ bb,
    const float* __restrict__ blin, float* __restrict__ hout,
    const float* __restrict__ Wlo, const float* __restrict__ Wro,
    const float* __restrict__ Wlino, const float* __restrict__ blino,
    float* __restrict__ xlo, float* __restrict__ xro, float* __restrict__ lino) {
    int wid = (blockIdx.x * blockDim.x + threadIdx.x) >> 6;
    int lane = threadIdx.x & 63;
    if (wid >= NN) return;
    int q = lane >> 4;    // quarter 0..3
    int ql = lane & 15;
    int c0 = ql * 8;

    float xrv[8], av[8];
    {
        float4 t0 = *reinterpret_cast<const float4*>(xr + (size_t)wid * DD + c0);
        float4 t1 = *reinterpret_cast<const float4*>(xr + (size_t)wid * DD + c0 + 4);
        xrv[0] = t0.x; xrv[1] = t0.y; xrv[2] = t0.z; xrv[3] = t0.w;
        xrv[4] = t1.x; xrv[5] = t1.y; xrv[6] = t1.z; xrv[7] = t1.w;
        float4 a0 = *reinterpret_cast<const float4*>(att + c0);
        float4 a1 = *reinterpret_cast<const float4*>(att + c0 + 4);
        av[0] = a0.x; av[1] = a0.y; av[2] = a0.z; av[3] = a0.w;
        av[4] = a1.x; av[5] = a1.y; av[6] = a1.z; av[7] = a1.w;
    }

    int start = offs[wid];
    int deg = offs[wid + 1] - start;

    float ss = 0.f;
    float acc[8];
#pragma unroll
    for (int c = 0; c < 8; c++) acc[c] = 0.f;

    // 8 edges per iteration (2 per quarter), both gathers issued before consume
    for (int base = 0; base < deg; base += 8) {
        int j0 = base + q, j1 = base + 4 + q;
        bool ok0 = j0 < deg, ok1 = j1 < deg;
        int s0 = ok0 ? csr_src[start + j0] : 0;
        int s1 = ok1 ? csr_src[start + j1] : 0;
        uint4 xp0 = *reinterpret_cast<const uint4*>(xlb + (size_t)s0 * DD + c0);
        uint4 xp1 = *reinterpret_cast<const uint4*>(xlb + (size_t)s1 * DD + c0);
        float xv0[8], xv1[8];
        unpack8(xp0, xv0);
        unpack8(xp1, xv1);
        float v0 = 0.f, v1 = 0.f;
#pragma unroll
        for (int c = 0; c < 8; c++) {
            float u0 = xv0[c] + xrv[c];
            float u1 = xv1[c] + xrv[c];
            v0 += fmaxf(u0, SLOPE * u0) * av[c];
            v1 += fmaxf(u1, SLOPE * u1) * av[c];
        }
#pragma unroll
        for (int msk = 1; msk < 16; msk <<= 1) {
            v0 += __shfl_xor(v0, msk, 64);
            v1 += __shfl_xor(v1, msk, 64);
        }
        float p0 = ok0 ? __expf(v0) : 0.f;
        float p1 = ok1 ? __expf(v1) : 0.f;
        ss += p0 + p1;
#pragma unroll
        for (int c = 0; c < 8; c++) acc[c] += p0 * xv0[c] + p1 * xv1[c];
    }

    // merge the 4 quarter-states (plain sums, no-max softmax)
#pragma unroll
    for (int msk = 16; msk < 64; msk <<= 1) {
        ss += __shfl_xor(ss, msk, 64);
#pragma unroll
        for (int c = 0; c < 8; c++) acc[c] += __shfl_xor(acc[c], msk, 64);
    }

    if (q == 0) {
        float inv = 1.f / (ss + 1e-16f);
        float4 l0 = *reinterpret_cast<const float4*>(lin + (size_t)wid * DD + c0);
        float4 l1 = *reinterpret_cast<const float4*>(lin + (size_t)wid * DD + c0 + 4);
        float4 b0 = *reinterpret_cast<const float4*>(bb + c0);
        float4 b1 = *reinterpret_cast<const float4*>(bb + c0 + 4);
        float4 bl0 = *reinterpret_cast<const float4*>(blin + c0);
        float4 bl1 = *reinterpret_cast<const float4*>(blin + c0 + 4);
        float lv[8] = {l0.x, l0.y, l0.z, l0.w, l1.x, l1.y, l1.z, l1.w};
        float bv[8] = {b0.x, b0.y, b0.z, b0.w, b1.x, b1.y, b1.z, b1.w};
        float blv[8] = {bl0.x, bl0.y, bl0.z, bl0.w, bl1.x, bl1.y, bl1.z, bl1.w};
        float o[8];
#pragma unroll
        for (int c = 0; c < 8; c++) o[c] = fmaxf(acc[c] * inv + bv[c] + lv[c] + blv[c], 0.f);

        if (!OUTVEC) {
            float4 s0 = make_float4(o[0], o[1], o[2], o[3]);
            float4 s1 = make_float4(o[4], o[5], o[6], o[7]);
            *reinterpret_cast<float4*>(hout + (size_t)wid * DD + c0) = s0;
            *reinterpret_cast<float4*>(hout + (size_t)wid * DD + c0 + 4) = s1;
        } else {
            // fused output-layer matvecs: d = h . W (128-length dots)
            float4 w0a = *reinterpret_cast<const float4*>(Wlo + c0);
            float4 w0b = *reinterpret_cast<const float4*>(Wlo + c0 + 4);
            float4 w1a = *reinterpret_cast<const float4*>(Wro + c0);
            float4 w1b = *reinterpret_cast<const float4*>(Wro + c0 + 4);
            float4 w2a = *reinterpret_cast<const float4*>(Wlino + c0);
            float4 w2b = *reinterpret_cast<const float4*>(Wlino + c0 + 4);
            float wv0[8] = {w0a.x, w0a.y, w0a.z, w0a.w, w0b.x, w0b.y, w0b.z, w0b.w};
            float wv1[8] = {w1a.x, w1a.y, w1a.z, w1a.w, w1b.x, w1b.y, w1b.z, w1b.w};
            float wv2[8] = {w2a.x, w2a.y, w2a.z, w2a.w, w2b.x, w2b.y, w2b.z, w2b.w};
            float d0 = 0.f, d1 = 0.f, d2 = 0.f;
#pragma unroll
            for (int c = 0; c < 8; c++) {
                d0 += o[c] * wv0[c];
                d1 += o[c] * wv1[c];
                d2 += o[c] * wv2[c];
            }
#pragma unroll
            for (int msk = 1; msk < 16; msk <<= 1) {
                d0 += __shfl_xor(d0, msk, 64);
                d1 += __shfl_xor(d1, msk, 64);
                d2 += __shfl_xor(d2, msk, 64);
            }
            if (ql == 0) {
                xlo[wid] = d0;
                xro[wid] = d1;
                lino[wid] = d2 + blino[0];
            }
        }
    }
}

// ---------------- fused output-layer logits + softmax (no-max) + aggregate ----------------
__global__ __launch_bounds__(256) void k_aggout(
    const int* __restrict__ offs, const int* __restrict__ csr_src,
    const float* __restrict__ xlo, const float* __restrict__ xro,
    const float* __restrict__ atto, const float* __restrict__ lino,
    const float* __restrict__ bo, float* __restrict__ out) {
    int wid = (blockIdx.x * blockDim.x + threadIdx.x) >> 6;
    int lane = threadIdx.x & 63;
    if (wid >= NN) return;
    int start = offs[wid];
    int deg = offs[wid + 1] - start;
    float xro_w = xro[wid];
    float a0 = atto[0];

    float sl = 0.f, nl = 0.f;
    for (int j = lane; j < deg; j += 64) {
        int s = csr_src[start + j];
        float xs = xlo[s];
        float u = xs + xro_w;
        float e = fmaxf(u, SLOPE * u) * a0;
        float p = __expf(e);
        sl += p;
        nl += p * xs;
    }
    sl = wred_sum(sl);
    nl = wred_sum(nl);
    if (lane == 0) out[wid] = nl / (sl + 1e-16f) + bo[0] + lino[wid];
}

extern "C" void kernel_launch(void* const* d_in, const int* in_sizes, int n_in,
                              void* d_out, int out_size, void* d_ws, size_t ws_size,
                              hipStream_t stream) {
    const float* x = (const float*)d_in[0];
    const int* ei = (const int*)d_in[1];
    const int* srcv = ei;
    const int* dstv = ei + EE;
    const float* Wl1 = (const float*)d_in[2];
    const float* Wr1 = (const float*)d_in[3];
    const float* att1 = (const float*)d_in[4];
    const float* b1 = (const float*)d_in[5];
    const float* Wlin1 = (const float*)d_in[6];
    const float* blin1 = (const float*)d_in[7];
    const float* Wl2 = (const float*)d_in[8];
    const float* Wr2 = (const float*)d_in[9];
    const float* att2 = (const float*)d_in[10];
    const float* b2 = (const float*)d_in[11];
    const float* Wlin2 = (const float*)d_in[12];
    const float* blin2 = (const float*)d_in[13];
    const float* Wlo = (const float*)d_in[14];
    const float* Wro = (const float*)d_in[15];
    const float* atto = (const float*)d_in[16];
    const float* bo = (const float*)d_in[17];
    const float* Wlino = (const float*)d_in[18];
    const float* blino = (const float*)d_in[19];

    char* w = (char*)d_ws;
    auto alloc = [&](size_t bytes) {
        void* p = (void*)w;
        w += (bytes + 255) & ~(size_t)255;
        return p;
    };
    ushort* xlb = (ushort*)alloc((size_t)NN * DD * 2);   // bf16 messages
    float* xr = (float*)alloc((size_t)NN * DD * 4);
    float* lin = (float*)alloc((size_t)NN * DD * 4);
    float* h = (float*)alloc((size_t)NN * DD * 4);
    ushort* Wt = (ushort*)alloc((size_t)6 * DD * DD * 2);
    float* xlo = (float*)alloc((size_t)NN * 4);
    float* xro = (float*)alloc((size_t)NN * 4);
    float* lino = (float*)alloc((size_t)NN * 4);
    int* deg = (int*)alloc((size_t)NN * 4);
    int* offs = (int*)alloc((size_t)(NN + 1) * 4);
    int* bsum = (int*)alloc(256 * 4);
    int* boff = (int*)alloc(256 * 4);
    int* csr_src = (int*)alloc((size_t)(EE + 8) * 4);
    int* epos = (int*)alloc((size_t)EE * 4);

    const int NB = (NN + 255) / 256;  // 196

    // CSR build
    hipMemsetAsync(deg, 0, (size_t)NN * 4, stream);
    k_degree<<<(EE + 255) / 256, 256, 0, stream>>>(dstv, deg, epos);
    k_blocksum<<<NB, 256, 0, stream>>>(deg, bsum);
    k_scan_bsum<<<1, 256, 0, stream>>>(bsum, boff, NB);
    k_scan_final<<<NB, 256, 0, stream>>>(deg, boff, offs);
    k_scatter<<<(EE + 255) / 256, 256, 0, stream>>>(srcv, dstv, offs, epos, csr_src);

    // weights -> transposed bf16
    k_wconvert<<<(6 * DD * DD) / 256, 256, 0, stream>>>(Wl1, Wr1, Wlin1, Wl2, Wr2, Wlin2, Wt);

    const int GEMM_GRID = (NN + 127) / 128;          // 391
    const int NODE_GRID = (NN * 64 + 255) / 256;     // 12500

    // layer 1
    k_gemm3m<<<GEMM_GRID, 256, 0, stream>>>(x, Wt + (size_t)0 * 3 * DD * DD, xlb, xr, lin);
    k_fused<0><<<NODE_GRID, 256, 0, stream>>>(offs, csr_src, xlb, xr, att1, lin, b1, blin1, h,
                                              nullptr, nullptr, nullptr, nullptr,
                                              nullptr, nullptr, nullptr);
    // layer 2 (+fused output matvecs; h never stored)
    k_gemm3m<<<GEMM_GRID, 256, 0, stream>>>(h, Wt + (size_t)1 * 3 * DD * DD, xlb, xr, lin);
    k_fused<1><<<NODE_GRID, 256, 0, stream>>>(offs, csr_src, xlb, xr, att2, lin, b2, blin2, nullptr,
                                              Wlo, Wro, Wlino, blino, xlo, xro, lino);
    // output layer aggregation
    k_aggout<<<NODE_GRID, 256, 0, stream>>>(offs, csr_src, xlo, xro, atto, lino, bo, (float*)d_out);
}

// Round 4
// 220.174 us; speedup vs baseline: 3.4464x; 1.0691x over previous
//
#include <hip/hip_runtime.h>
#include <hip/hip_bf16.h>
#include <math.h>

#define NN 50000
#define EE 800000
#define DD 128
#define SLOPE 0.2f

typedef __attribute__((ext_vector_type(8))) short short8;   // 8 bf16 (4 VGPRs)
typedef __attribute__((ext_vector_type(4))) float f32x4;    // MFMA acc

static __device__ __forceinline__ float wred_sum(float v) {
#pragma unroll
    for (int m = 1; m < 64; m <<= 1) v += __shfl_xor(v, m, 64);
    return v;
}

static __device__ __forceinline__ ushort f2bf(float f) {
    __hip_bfloat16 b = __float2bfloat16(f);
    return *reinterpret_cast<ushort*>(&b);
}
static __device__ __forceinline__ float bf2f(unsigned int u) {
    return __uint_as_float((u & 0xffffu) << 16);
}
static __device__ __forceinline__ void unpack8(const uint4& xp, float* xv) {
    xv[0] = bf2f(xp.x); xv[1] = bf2f(xp.x >> 16);
    xv[2] = bf2f(xp.y); xv[3] = bf2f(xp.y >> 16);
    xv[4] = bf2f(xp.z); xv[5] = bf2f(xp.z >> 16);
    xv[6] = bf2f(xp.w); xv[7] = bf2f(xp.w >> 16);
}

// ---------------- CSR build ----------------
__global__ void k_degree(const int* __restrict__ dstv, int* __restrict__ deg,
                         int* __restrict__ epos) {
    int i = blockIdx.x * blockDim.x + threadIdx.x;
    if (i < EE) epos[i] = atomicAdd(&deg[dstv[i]], 1);
}

__global__ void k_blocksum(const int* __restrict__ deg, int* __restrict__ bsum) {
    int t = threadIdx.x;
    int idx = blockIdx.x * 256 + t;
    int v = (idx < NN) ? deg[idx] : 0;
#pragma unroll
    for (int m = 1; m < 64; m <<= 1) v += __shfl_xor(v, m, 64);
    __shared__ int part[4];
    if ((t & 63) == 0) part[t >> 6] = v;
    __syncthreads();
    if (t == 0) bsum[blockIdx.x] = part[0] + part[1] + part[2] + part[3];
}

__global__ void k_scan_bsum(const int* __restrict__ bsum, int* __restrict__ boff, int nb) {
    __shared__ int sd[2][256];
    int t = threadIdx.x;
    int v = (t < nb) ? bsum[t] : 0;
    sd[0][t] = v;
    __syncthreads();
    int s = 0;
    for (int off = 1; off < 256; off <<= 1) {
        int x = sd[s][t];
        if (t >= off) x += sd[s][t - off];
        sd[s ^ 1][t] = x;
        s ^= 1;
        __syncthreads();
    }
    if (t < nb) boff[t] = sd[s][t] - v;  // exclusive
}

__global__ void k_scan_final(const int* __restrict__ deg, const int* __restrict__ boff,
                             int* __restrict__ offs) {
    __shared__ int sd[2][256];
    int t = threadIdx.x;
    int idx = blockIdx.x * 256 + t;
    int v = (idx < NN) ? deg[idx] : 0;
    sd[0][t] = v;
    __syncthreads();
    int s = 0;
    for (int off = 1; off < 256; off <<= 1) {
        int x = sd[s][t];
        if (t >= off) x += sd[s][t - off];
        sd[s ^ 1][t] = x;
        s ^= 1;
        __syncthreads();
    }
    int incl = sd[s][t];
    int base = boff[blockIdx.x];
    if (idx < NN) offs[idx + 1] = base + incl;
    if (idx == 0) offs[0] = 0;
}

__global__ void k_scatter(const int* __restrict__ srcv, const int* __restrict__ dstv,
                          const int* __restrict__ offs, const int* __restrict__ epos,
                          int* __restrict__ csr_src) {
    int i = blockIdx.x * blockDim.x + threadIdx.x;
    if (i < EE) csr_src[offs[dstv[i]] + epos[i]] = srcv[i];
}

// ---------------- weight convert: Wt[i][n][k] = bf16(W_i[k][n]) ----------------
__global__ __launch_bounds__(256) void k_wconvert(
    const float* __restrict__ W0, const float* __restrict__ W1, const float* __restrict__ W2,
    const float* __restrict__ W3, const float* __restrict__ W4, const float* __restrict__ W5,
    ushort* __restrict__ Wt) {
    int idx = blockIdx.x * 256 + threadIdx.x;  // 6*16384
    int i = idx >> 14;
    int r = idx & 16383;
    int n = r >> 7;
    int k = r & 127;
    const float* Ws[6] = {W0, W1, W2, W3, W4, W5};
    Wt[idx] = f2bf(Ws[i][k * DD + n]);
}

// ---------------- MFMA 3-matrix GEMM with LDS-staged weights ----------------
// block=256 (4 waves), each wave: 32 rows x 128 cols. K=128.
// XBF=0: X fp32 (convert inline). XBF=1: X bf16 (direct short8 loads).
template <int XBF>
__global__ __launch_bounds__(256) void k_gemm3m(
    const float* __restrict__ Xf,     // [NN][128] fp32   (XBF=0)
    const ushort* __restrict__ Xb,    // [NN][128] bf16   (XBF=1)
    const ushort* __restrict__ Wt,    // [3][128][128] bf16, [n][k] layout
    ushort* __restrict__ O0b,         // xl bf16
    float* __restrict__ O1,           // xr fp32
    float* __restrict__ O2) {         // lin fp32
    __shared__ ushort wsh[128 * 136];  // +8 shorts/row pad -> balanced banks
    int t = threadIdx.x;
    int wid = t >> 6, lane = t & 63;
    int m0 = blockIdx.x * 128 + wid * 32;
    int qrow = lane & 15, kg = lane >> 4;

    // A fragments: 2 m-tiles x 4 k-steps
    short8 afrag[2][4];
#pragma unroll
    for (int mg = 0; mg < 2; mg++) {
#pragma unroll
        for (int ks = 0; ks < 4; ks++) {
            int row = m0 + mg * 16 + qrow;
            row = (row < NN) ? row : (NN - 1);  // clamp (stores predicated)
            if (XBF) {
                afrag[mg][ks] = *reinterpret_cast<const short8*>(
                    Xb + (size_t)row * DD + ks * 32 + kg * 8);
            } else {
                const float* p = Xf + (size_t)row * DD + ks * 32 + kg * 8;
                float4 u0 = *reinterpret_cast<const float4*>(p);
                float4 u1 = *reinterpret_cast<const float4*>(p + 4);
                short8 s;
                s[0] = (short)f2bf(u0.x); s[1] = (short)f2bf(u0.y);
                s[2] = (short)f2bf(u0.z); s[3] = (short)f2bf(u0.w);
                s[4] = (short)f2bf(u1.x); s[5] = (short)f2bf(u1.y);
                s[6] = (short)f2bf(u1.z); s[7] = (short)f2bf(u1.w);
                afrag[mg][ks] = s;
            }
        }
    }

    for (int w = 0; w < 3; w++) {
        __syncthreads();  // previous iter done reading wsh
        const ushort* Wb = Wt + (size_t)w * DD * DD;
#pragma unroll
        for (int i = 0; i < 8; i++) {
            int flat = i * 256 + t;       // 0..2047 chunks of 8 shorts
            int row = flat >> 4, ch = flat & 15;
            short8 v = *reinterpret_cast<const short8*>(Wb + row * DD + ch * 8);
            *reinterpret_cast<short8*>(&wsh[row * 136 + ch * 8]) = v;
        }
        __syncthreads();

        f32x4 acc[2][8];
#pragma unroll
        for (int mg = 0; mg < 2; mg++)
#pragma unroll
            for (int ng = 0; ng < 8; ng++) acc[mg][ng] = (f32x4)(0.f);

#pragma unroll
        for (int ks = 0; ks < 4; ks++) {
            short8 bfrag[8];
#pragma unroll
            for (int ng = 0; ng < 8; ng++)
                bfrag[ng] = *reinterpret_cast<const short8*>(
                    &wsh[(ng * 16 + qrow) * 136 + ks * 32 + kg * 8]);
#pragma unroll
            for (int mg = 0; mg < 2; mg++)
#pragma unroll
                for (int ng = 0; ng < 8; ng++)
                    acc[mg][ng] = __builtin_amdgcn_mfma_f32_16x16x32_bf16(
                        afrag[mg][ks], bfrag[ng], acc[mg][ng], 0, 0, 0);
        }

        // store: row = m0 + mg*16 + kg*4 + r, col = ng*16 + qrow
#pragma unroll
        for (int mg = 0; mg < 2; mg++) {
#pragma unroll
            for (int r = 0; r < 4; r++) {
                int row = m0 + mg * 16 + kg * 4 + r;
                if (row < NN) {
#pragma unroll
                    for (int ng = 0; ng < 8; ng++) {
                        int col = ng * 16 + qrow;
                        float v = acc[mg][ng][r];
                        if (w == 0) O0b[(size_t)row * DD + col] = f2bf(v);
                        else if (w == 1) O1[(size_t)row * DD + col] = v;
                        else O2[(size_t)row * DD + col] = v;
                    }
                }
            }
        }
    }
}

// ---------------- fused logits + softmax (no-max) + aggregate + combine (+relu) ----------------
// Persistent grid-stride; wave per dst node; quarter-wave (16 lanes x 8 cols) per edge,
// rotating 1-deep row prefetch.
// OUTVEC=0: writes h as bf16. OUTVEC=1: fuses the three output-layer matvecs.
template <int OUTVEC>
__global__ __launch_bounds__(256, 8) void k_fused(
    const int* __restrict__ offs, const int* __restrict__ csr_src,
    const ushort* __restrict__ xlb,  // [NN][128] bf16 (messages + logit left)
    const float* __restrict__ xr,    // [NN][128] fp32 (logit right)
    const float* __restrict__ att,
    const float* __restrict__ lin, const float* __restrict__ bb,
    const float* __restrict__ blin, ushort* __restrict__ houtb,
    const float* __restrict__ Wlo, const float* __restrict__ Wro,
    const float* __restrict__ Wlino, const float* __restrict__ blino,
    float* __restrict__ xlo, float* __restrict__ xro, float* __restrict__ lino,
    int nwaves) {
    int gwave = (blockIdx.x * blockDim.x + threadIdx.x) >> 6;
    int lane = threadIdx.x & 63;
    int q = lane >> 4;    // quarter 0..3
    int ql = lane & 15;
    int c0 = ql * 8;

    float av[8];
    {
        float4 a0 = *reinterpret_cast<const float4*>(att + c0);
        float4 a1 = *reinterpret_cast<const float4*>(att + c0 + 4);
        av[0] = a0.x; av[1] = a0.y; av[2] = a0.z; av[3] = a0.w;
        av[4] = a1.x; av[5] = a1.y; av[6] = a1.z; av[7] = a1.w;
    }

    for (int wid = gwave; wid < NN; wid += nwaves) {
        int start = offs[wid];
        int deg = offs[wid + 1] - start;

        float xrv[8];
        {
            float4 t0 = *reinterpret_cast<const float4*>(xr + (size_t)wid * DD + c0);
            float4 t1 = *reinterpret_cast<const float4*>(xr + (size_t)wid * DD + c0 + 4);
            xrv[0] = t0.x; xrv[1] = t0.y; xrv[2] = t0.z; xrv[3] = t0.w;
            xrv[4] = t1.x; xrv[5] = t1.y; xrv[6] = t1.z; xrv[7] = t1.w;
        }

        float ss = 0.f;
        float acc[8];
#pragma unroll
        for (int c = 0; c < 8; c++) acc[c] = 0.f;

        // rotating prefetch: row for iter j in flight while computing nothing yet;
        // row for j+4 issued before consuming row j.
        int s_cur = (q < deg) ? csr_src[start + q] : 0;
        uint4 xp = *reinterpret_cast<const uint4*>(xlb + (size_t)s_cur * DD + c0);
        for (int j = q; j < deg; j += 4) {
            int jn = j + 4;
            int s_nxt = (jn < deg) ? csr_src[start + jn] : 0;
            uint4 xpn = *reinterpret_cast<const uint4*>(xlb + (size_t)s_nxt * DD + c0);
            float xv[8];
            unpack8(xp, xv);
            float v = 0.f;
#pragma unroll
            for (int c = 0; c < 8; c++) {
                float u = xv[c] + xrv[c];
                v += fmaxf(u, SLOPE * u) * av[c];
            }
#pragma unroll
            for (int msk = 1; msk < 16; msk <<= 1) v += __shfl_xor(v, msk, 64);
            float p = __expf(v);
            ss += p;
#pragma unroll
            for (int c = 0; c < 8; c++) acc[c] += p * xv[c];
            xp = xpn;
        }

        // merge the 4 quarter-states (plain sums, no-max softmax)
#pragma unroll
        for (int msk = 16; msk < 64; msk <<= 1) {
            ss += __shfl_xor(ss, msk, 64);
#pragma unroll
            for (int c = 0; c < 8; c++) acc[c] += __shfl_xor(acc[c], msk, 64);
        }

        if (q == 0) {
            float inv = 1.f / (ss + 1e-16f);
            float4 l0 = *reinterpret_cast<const float4*>(lin + (size_t)wid * DD + c0);
            float4 l1 = *reinterpret_cast<const float4*>(lin + (size_t)wid * DD + c0 + 4);
            float4 b0 = *reinterpret_cast<const float4*>(bb + c0);
            float4 b1 = *reinterpret_cast<const float4*>(bb + c0 + 4);
            float4 bl0 = *reinterpret_cast<const float4*>(blin + c0);
            float4 bl1 = *reinterpret_cast<const float4*>(blin + c0 + 4);
            float lv[8] = {l0.x, l0.y, l0.z, l0.w, l1.x, l1.y, l1.z, l1.w};
            float bv[8] = {b0.x, b0.y, b0.z, b0.w, b1.x, b1.y, b1.z, b1.w};
            float blv[8] = {bl0.x, bl0.y, bl0.z, bl0.w, bl1.x, bl1.y, bl1.z, bl1.w};
            float o[8];
#pragma unroll
            for (int c = 0; c < 8; c++) o[c] = fmaxf(acc[c] * inv + bv[c] + lv[c] + blv[c], 0.f);

            if (!OUTVEC) {
                uint4 pk;
                pk.x = (unsigned)f2bf(o[0]) | ((unsigned)f2bf(o[1]) << 16);
                pk.y = (unsigned)f2bf(o[2]) | ((unsigned)f2bf(o[3]) << 16);
                pk.z = (unsigned)f2bf(o[4]) | ((unsigned)f2bf(o[5]) << 16);
                pk.w = (unsigned)f2bf(o[6]) | ((unsigned)f2bf(o[7]) << 16);
                *reinterpret_cast<uint4*>(houtb + (size_t)wid * DD + c0) = pk;
            } else {
                // fused output-layer matvecs: d = h . W (128-length dots)
                float4 w0a = *reinterpret_cast<const float4*>(Wlo + c0);
                float4 w0b = *reinterpret_cast<const float4*>(Wlo + c0 + 4);
                float4 w1a = *reinterpret_cast<const float4*>(Wro + c0);
                float4 w1b = *reinterpret_cast<const float4*>(Wro + c0 + 4);
                float4 w2a = *reinterpret_cast<const float4*>(Wlino + c0);
                float4 w2b = *reinterpret_cast<const float4*>(Wlino + c0 + 4);
                float wv0[8] = {w0a.x, w0a.y, w0a.z, w0a.w, w0b.x, w0b.y, w0b.z, w0b.w};
                float wv1[8] = {w1a.x, w1a.y, w1a.z, w1a.w, w1b.x, w1b.y, w1b.z, w1b.w};
                float wv2[8] = {w2a.x, w2a.y, w2a.z, w2a.w, w2b.x, w2b.y, w2b.z, w2b.w};
                float d0 = 0.f, d1 = 0.f, d2 = 0.f;
#pragma unroll
                for (int c = 0; c < 8; c++) {
                    d0 += o[c] * wv0[c];
                    d1 += o[c] * wv1[c];
                    d2 += o[c] * wv2[c];
                }
#pragma unroll
                for (int msk = 1; msk < 16; msk <<= 1) {
                    d0 += __shfl_xor(d0, msk, 64);
                    d1 += __shfl_xor(d1, msk, 64);
                    d2 += __shfl_xor(d2, msk, 64);
                }
                if (ql == 0) {
                    xlo[wid] = d0;
                    xro[wid] = d1;
                    lino[wid] = d2 + blino[0];
                }
            }
        }
    }
}

// ---------------- fused output-layer logits + softmax (no-max) + aggregate ----------------
__global__ __launch_bounds__(256) void k_aggout(
    const int* __restrict__ offs, const int* __restrict__ csr_src,
    const float* __restrict__ xlo, const float* __restrict__ xro,
    const float* __restrict__ atto, const float* __restrict__ lino,
    const float* __restrict__ bo, float* __restrict__ out) {
    int wid = (blockIdx.x * blockDim.x + threadIdx.x) >> 6;
    int lane = threadIdx.x & 63;
    if (wid >= NN) return;
    int start = offs[wid];
    int deg = offs[wid + 1] - start;
    float xro_w = xro[wid];
    float a0 = atto[0];

    float sl = 0.f, nl = 0.f;
    for (int j = lane; j < deg; j += 64) {
        int s = csr_src[start + j];
        float xs = xlo[s];
        float u = xs + xro_w;
        float e = fmaxf(u, SLOPE * u) * a0;
        float p = __expf(e);
        sl += p;
        nl += p * xs;
    }
    sl = wred_sum(sl);
    nl = wred_sum(nl);
    if (lane == 0) out[wid] = nl / (sl + 1e-16f) + bo[0] + lino[wid];
}

extern "C" void kernel_launch(void* const* d_in, const int* in_sizes, int n_in,
                              void* d_out, int out_size, void* d_ws, size_t ws_size,
                              hipStream_t stream) {
    const float* x = (const float*)d_in[0];
    const int* ei = (const int*)d_in[1];
    const int* srcv = ei;
    const int* dstv = ei + EE;
    const float* Wl1 = (const float*)d_in[2];
    const float* Wr1 = (const float*)d_in[3];
    const float* att1 = (const float*)d_in[4];
    const float* b1 = (const float*)d_in[5];
    const float* Wlin1 = (const float*)d_in[6];
    const float* blin1 = (const float*)d_in[7];
    const float* Wl2 = (const float*)d_in[8];
    const float* Wr2 = (const float*)d_in[9];
    const float* att2 = (const float*)d_in[10];
    const float* b2 = (const float*)d_in[11];
    const float* Wlin2 = (const float*)d_in[12];
    const float* blin2 = (const float*)d_in[13];
    const float* Wlo = (const float*)d_in[14];
    const float* Wro = (const float*)d_in[15];
    const float* atto = (const float*)d_in[16];
    const float* bo = (const float*)d_in[17];
    const float* Wlino = (const float*)d_in[18];
    const float* blino = (const float*)d_in[19];

    char* w = (char*)d_ws;
    auto alloc = [&](size_t bytes) {
        void* p = (void*)w;
        w += (bytes + 255) & ~(size_t)255;
        return p;
    };
    ushort* xlb = (ushort*)alloc((size_t)NN * DD * 2);   // bf16 messages
    float* xr = (float*)alloc((size_t)NN * DD * 4);
    float* lin = (float*)alloc((size_t)NN * DD * 4);
    ushort* hb = (ushort*)alloc((size_t)NN * DD * 2);    // hidden state, bf16
    ushort* Wt = (ushort*)alloc((size_t)6 * DD * DD * 2);
    float* xlo = (float*)alloc((size_t)NN * 4);
    float* xro = (float*)alloc((size_t)NN * 4);
    float* lino = (float*)alloc((size_t)NN * 4);
    int* deg = (int*)alloc((size_t)NN * 4);
    int* offs = (int*)alloc((size_t)(NN + 1) * 4);
    int* bsum = (int*)alloc(256 * 4);
    int* boff = (int*)alloc(256 * 4);
    int* csr_src = (int*)alloc((size_t)(EE + 8) * 4);
    int* epos = (int*)alloc((size_t)EE * 4);

    const int NB = (NN + 255) / 256;  // 196

    // CSR build
    hipMemsetAsync(deg, 0, (size_t)NN * 4, stream);
    k_degree<<<(EE + 255) / 256, 256, 0, stream>>>(dstv, deg, epos);
    k_blocksum<<<NB, 256, 0, stream>>>(deg, bsum);
    k_scan_bsum<<<1, 256, 0, stream>>>(bsum, boff, NB);
    k_scan_final<<<NB, 256, 0, stream>>>(deg, boff, offs);
    k_scatter<<<(EE + 255) / 256, 256, 0, stream>>>(srcv, dstv, offs, epos, csr_src);

    // weights -> transposed bf16
    k_wconvert<<<(6 * DD * DD) / 256, 256, 0, stream>>>(Wl1, Wr1, Wlin1, Wl2, Wr2, Wlin2, Wt);

    const int GEMM_GRID = (NN + 127) / 128;          // 391
    const int NODE_GRID = (NN * 64 + 255) / 256;     // 12500
    const int PERS_BLOCKS = 2048;                    // 8192 waves = 32/CU
    const int PERS_WAVES = PERS_BLOCKS * 4;

    // layer 1
    k_gemm3m<0><<<GEMM_GRID, 256, 0, stream>>>(x, nullptr, Wt + (size_t)0 * 3 * DD * DD,
                                               xlb, xr, lin);
    k_fused<0><<<PERS_BLOCKS, 256, 0, stream>>>(offs, csr_src, xlb, xr, att1, lin, b1, blin1, hb,
                                                nullptr, nullptr, nullptr, nullptr,
                                                nullptr, nullptr, nullptr, PERS_WAVES);
    // layer 2 (+fused output matvecs)
    k_gemm3m<1><<<GEMM_GRID, 256, 0, stream>>>(nullptr, hb, Wt + (size_t)1 * 3 * DD * DD,
                                               xlb, xr, lin);
    k_fused<1><<<PERS_BLOCKS, 256, 0, stream>>>(offs, csr_src, xlb, xr, att2, lin, b2, blin2,
                                                nullptr, Wlo, Wro, Wlino, blino,
                                                xlo, xro, lino, PERS_WAVES);
    // output layer aggregation
    k_aggout<<<NODE_GRID, 256, 0, stream>>>(offs, csr_src, xlo, xro, atto, lino, bo, (float*)d_out);
}